// Round 13
// baseline (230.566 us; speedup 1.0000x reference)
//
#include <hip/hip_runtime.h>
#include <hip/hip_bf16.h>

#define B_  2
#define T_  4096
#define C_  768
#define H_  12
#define D_  64
#define MTOT (B_*T_)   // 8192

typedef __bf16 bf16;
typedef __bf16 bf16x8 __attribute__((ext_vector_type(8)));
typedef __bf16 bf16x4 __attribute__((ext_vector_type(4)));
typedef float  f32x4  __attribute__((ext_vector_type(4)));
typedef unsigned int u32x4 __attribute__((ext_vector_type(4)));

// async global->LDS, 16B per lane; LDS dest must be wave-uniform base + lane*16
__device__ __forceinline__ void gl_lds16(const bf16* g, bf16* l) {
    __builtin_amdgcn_global_load_lds(
        (const __attribute__((address_space(1))) void*)g,
        (__attribute__((address_space(3))) void*)l, 16, 0, 0);
}

// ---- P redistribution via permlane-swap BUILTINS ----
__device__ __forceinline__ void pswap32_16(unsigned int& x, unsigned int& y) {
    auto r1 = __builtin_amdgcn_permlane32_swap(x, y, false, false);
    auto r2 = __builtin_amdgcn_permlane16_swap(r1[0], r1[1], false, false);
    x = r2[0]; y = r2[1];
}
__device__ __forceinline__ unsigned int cvtpk(float lo, float hi) {
    unsigned int r;
    asm("v_cvt_pk_bf16_f32 %0, %1, %2" : "=v"(r) : "v"(lo), "v"(hi));
    return r;
}

// ---------------- fp32 -> bf16 convert ----------------
__global__ __launch_bounds__(256) void cvt_bf16(const float* __restrict__ src,
                                                bf16* __restrict__ dst, int n8) {
    int i = blockIdx.x * 256 + threadIdx.x;
    if (i >= n8) return;
    const float4* s4 = (const float4*)src;
    float4 a = s4[2*(size_t)i], b = s4[2*(size_t)i+1];
    bf16x8 o;
    o[0]=(bf16)a.x; o[1]=(bf16)a.y; o[2]=(bf16)a.z; o[3]=(bf16)a.w;
    o[4]=(bf16)b.x; o[5]=(bf16)b.y; o[6]=(bf16)b.z; o[7]=(bf16)b.w;
    *(bf16x8*)(dst + 8*(size_t)i) = o;
}

__global__ __launch_bounds__(256) void cvt_bf16_w4(const float* __restrict__ w0,
                                                   const float* __restrict__ w1,
                                                   const float* __restrict__ w2,
                                                   const float* __restrict__ w3,
                                                   bf16* __restrict__ d0,
                                                   bf16* __restrict__ d1,
                                                   bf16* __restrict__ d2,
                                                   bf16* __restrict__ d3) {
    int z = blockIdx.y;
    const float* src = (z==0)?w0:(z==1)?w1:(z==2)?w2:w3;
    bf16* dst = (z==0)?d0:(z==1)?d1:(z==2)?d2:d3;
    int i = blockIdx.x * 256 + threadIdx.x;
    const float4* s4 = (const float4*)src;
    float4 a = s4[2*(size_t)i], b = s4[2*(size_t)i+1];
    bf16x8 o;
    o[0]=(bf16)a.x; o[1]=(bf16)a.y; o[2]=(bf16)a.z; o[3]=(bf16)a.w;
    o[4]=(bf16)b.x; o[5]=(bf16)b.y; o[6]=(bf16)b.z; o[7]=(bf16)b.w;
    *(bf16x8*)(dst + 8*(size_t)i) = o;
}

// ---------------- QKV projection GEMM (round-13: 256x128 tile, 512 thr) -----
// Round-12: XCD swizzle neutral -> relabeling traffic's source doesn't help;
// REDUCE the volume. Staged bytes = grid x (BM+BN)x768x2B. BM 128->256
// (512 threads, 8 waves 4m x 2n) keeps the per-wave structure byte-identical
// to round-8 (acc[4][4], 8 ds_read_b128, 16 MFMA) while cutting the staged
// total 451 -> 332 MB (-26%). LDS 48KB, ~16 waves/CU (vs 18) — TLP flat.
// z=0 -> Q (pre-scaled by 0.125*log2e) in (B,H,T,D); z=1 -> K; z=2 -> V^T.
__global__ __launch_bounds__(512) void gemm_qkv(const bf16* __restrict__ xb,
                                                const bf16* __restrict__ wqb,
                                                const bf16* __restrict__ wkb,
                                                const bf16* __restrict__ wvb,
                                                bf16* __restrict__ qo,
                                                bf16* __restrict__ ko,
                                                bf16* __restrict__ vto) {
    int z = blockIdx.z;
    const bf16* w = (z == 0) ? wqb : (z == 1) ? wkb : wvb;
    bf16* dst = (z == 0) ? qo : (z == 1) ? ko : vto;
    int mbase = blockIdx.x * 256;
    int nbase = blockIdx.y * 128;
    __shared__ bf16 As[2][256][32];   // UNPADDED: global_load_lds lane-contiguous
    __shared__ bf16 Bs[2][128][32];
    int tid  = threadIdx.x;           // 0..511
    int wave = tid >> 6, lane = tid & 63;
    int wm = (wave >> 1) * 64, wn = (wave & 1) * 64;   // 4m x 2n wave layout
    int lr = lane & 15, lg = lane >> 4;
    int srow = tid >> 2, scol = tid & 3;               // 128 rows x 4 chunks
    const bf16* xa0 = xb + (size_t)(mbase + srow) * C_ + scol * 8;
    const bf16* xa1 = xb + (size_t)(mbase + 128 + srow) * C_ + scol * 8;
    const bf16* wa0 = w  + (size_t)(nbase + srow) * C_ + scol * 8;
#define GSTAGE(kb_, cb_) do { \
        gl_lds16(xa0 + (kb_), &As[cb_][srow][scol * 8]); \
        gl_lds16(xa1 + (kb_), &As[cb_][128 + srow][scol * 8]); \
        gl_lds16(wa0 + (kb_), &Bs[cb_][srow][scol * 8]); \
    } while (0)
    f32x4 acc[4][4] = {};
    GSTAGE(0, 0);
    __syncthreads();               // drain DMA for tile 0
    int cur = 0;
    for (int kb = 0; kb < C_; kb += 32) {
        if (kb + 32 < C_) GSTAGE(kb + 32, cur ^ 1);   // DMA overlaps compute
        bf16x8 af[4], bfr[4];
        #pragma unroll
        for (int mt = 0; mt < 4; ++mt) af[mt]  = *(const bf16x8*)(&As[cur][wm + mt*16 + lr][lg*8]);
        #pragma unroll
        for (int nt = 0; nt < 4; ++nt) bfr[nt] = *(const bf16x8*)(&Bs[cur][wn + nt*16 + lr][lg*8]);
        #pragma unroll
        for (int mt = 0; mt < 4; ++mt)
            #pragma unroll
            for (int nt = 0; nt < 4; ++nt)
                acc[mt][nt] = __builtin_amdgcn_mfma_f32_16x16x32_bf16(af[mt], bfr[nt], acc[mt][nt], 0, 0, 0);
        __syncthreads();           // next-tile DMA landed + all reads of cur done
        cur ^= 1;
    }
#undef GSTAGE
    float sc = (z == 0) ? 0.18033688011112042f : 1.0f;  // 0.125*log2(e) folded into Q
    int m0 = mbase + wm + (lg << 2);
    int n0 = nbase + wn + lr;
    if (z < 2) {
        #pragma unroll
        for (int mt = 0; mt < 4; ++mt) {
            #pragma unroll
            for (int nt = 0; nt < 4; ++nt) {
                int n = n0 + nt * 16;
                int h = n >> 6, d = n & 63;
                #pragma unroll
                for (int r = 0; r < 4; ++r) {
                    int m = m0 + mt * 16 + r;
                    int b = m >> 12, t = m & 4095;
                    dst[(((size_t)b * H_ + h) * T_ + t) * 64 + d] = (bf16)(acc[mt][nt][r] * sc);
                }
            }
        }
    } else {
        #pragma unroll
        for (int mt = 0; mt < 4; ++mt) {
            int m = m0 + mt * 16;
            int b = m >> 12, t = m & 4095;
            #pragma unroll
            for (int nt = 0; nt < 4; ++nt) {
                int n = n0 + nt * 16;
                int h = n >> 6, d = n & 63;
                bf16x4 pk;
                #pragma unroll
                for (int r = 0; r < 4; ++r) pk[r] = (bf16)acc[mt][nt][r];
                *(bf16x4*)(dst + (((size_t)b * H_ + h) * 64 + d) * T_ + t) = pk;
            }
        }
    }
}

// ---------------- output projection GEMM (round-8 structure, no swizzle) ----
// BM=256 here would leave 64 CUs idle (grid 192); 128^2 grid=384 kept.
__global__ __launch_bounds__(256) void gemm_out(const bf16* __restrict__ ctx,
                                                const bf16* __restrict__ wob,
                                                float* __restrict__ out) {
    int mbase = blockIdx.x * 128;
    int nbase = blockIdx.y * 128;
    __shared__ bf16 As[2][128][32];
    __shared__ bf16 Bs[2][128][32];
    int tid  = threadIdx.x;
    int wave = tid >> 6, lane = tid & 63;
    int wm = (wave >> 1) * 64, wn = (wave & 1) * 64;
    int lr = lane & 15, lg = lane >> 4;
    int srow0 = tid >> 2, scol0 = tid & 3;
    int srow1 = (tid + 256) >> 2, scol1 = (tid + 256) & 3;
    const bf16* xa0 = ctx + (size_t)(mbase + srow0) * C_ + scol0 * 8;
    const bf16* xa1 = ctx + (size_t)(mbase + srow1) * C_ + scol1 * 8;
    const bf16* wa0 = wob + (size_t)(nbase + srow0) * C_ + scol0 * 8;
    const bf16* wa1 = wob + (size_t)(nbase + srow1) * C_ + scol1 * 8;
#define GSTAGE(kb_, cb_) do { \
        gl_lds16(xa0 + (kb_), &As[cb_][srow0][scol0 * 8]); \
        gl_lds16(xa1 + (kb_), &As[cb_][srow1][scol1 * 8]); \
        gl_lds16(wa0 + (kb_), &Bs[cb_][srow0][scol0 * 8]); \
        gl_lds16(wa1 + (kb_), &Bs[cb_][srow1][scol1 * 8]); \
    } while (0)
    f32x4 acc[4][4] = {};
    GSTAGE(0, 0);
    __syncthreads();
    int cur = 0;
    for (int kb = 0; kb < C_; kb += 32) {
        if (kb + 32 < C_) GSTAGE(kb + 32, cur ^ 1);
        bf16x8 af[4], bfr[4];
        #pragma unroll
        for (int mt = 0; mt < 4; ++mt) af[mt]  = *(const bf16x8*)(&As[cur][wm + mt*16 + lr][lg*8]);
        #pragma unroll
        for (int nt = 0; nt < 4; ++nt) bfr[nt] = *(const bf16x8*)(&Bs[cur][wn + nt*16 + lr][lg*8]);
        #pragma unroll
        for (int mt = 0; mt < 4; ++mt)
            #pragma unroll
            for (int nt = 0; nt < 4; ++nt)
                acc[mt][nt] = __builtin_amdgcn_mfma_f32_16x16x32_bf16(af[mt], bfr[nt], acc[mt][nt], 0, 0, 0);
        __syncthreads();
        cur ^= 1;
    }
#undef GSTAGE
    int m0 = mbase + wm + (lg << 2);
    int n0 = nbase + wn + lr;
    #pragma unroll
    for (int mt = 0; mt < 4; ++mt)
        #pragma unroll
        for (int nt = 0; nt < 4; ++nt)
            #pragma unroll
            for (int r = 0; r < 4; ++r)
                out[(size_t)(m0 + mt * 16 + r) * C_ + n0 + nt * 16] = acc[mt][nt][r];
}

// ---------------- causal flash attention (round-10 version, kept) -----------
// 87 µs: DMA-staged dbuf, XOR-swizzle (0 conflicts), fixed-max exp2 softmax,
// in-register P via permlane, l-sum on the MFMA pipe (A=ones).
__device__ __forceinline__ void attn_store(const f32x4 (&o)[4], float l, bf16* __restrict__ ctx,
                                           int b, int qrow, int h, int lg) {
    float inv = 1.0f / l;
    #pragma unroll
    for (int dt = 0; dt < 4; ++dt) {
        bf16x4 pk;
        #pragma unroll
        for (int r = 0; r < 4; ++r) pk[r] = (bf16)(o[dt][r] * inv);
        *(bf16x4*)(ctx + ((size_t)b * T_ + qrow) * C_ + h * 64 + dt * 16 + lg * 4) = pk;
    }
}

__global__ __launch_bounds__(256) void attn(const bf16* __restrict__ q,
                                            const bf16* __restrict__ k,
                                            const bf16* __restrict__ vt,
                                            bf16* __restrict__ ctx) {
    int idx = blockIdx.x;          // 0..1535
    int qt = 63 - idx / 24;        // globally sorted descending work
    int bh = idx % 24;
    int b = bh / H_, h = bh % H_;
    int tid = threadIdx.x;
    int wave = tid >> 6, lane = tid & 63;
    int lr = lane & 15, lg = lane >> 4;

    __shared__ bf16 Ks[2][64][64]; // double-buffered K tile (keys x d), swizzled
    __shared__ bf16 Vs[2][64][64]; // double-buffered V^T tile (d x keys), swizzled

    const bf16* qp = q  + (size_t)bh * T_ * 64;
    const bf16* kp = k  + (size_t)bh * T_ * 64;
    const bf16* vp = vt + (size_t)bh * 64 * (size_t)T_;

    // staging: thread tid owns LDS 16B chunk (row r0, chunk c0) = linear tid*16;
    // source column pre-swizzled so LDS[row][j] = G[row][j ^ (row&7)]
    int r0 = tid >> 3, c0 = tid & 7;
    int cs = (c0 ^ (r0 & 7)) * 8;                    // swizzled source col (elems)
    const bf16* kstg = kp + (size_t)r0 * 64 + cs;
    const bf16* vstg = vp + (size_t)r0 * T_ + cs;

#define STAGE(kb_, cb_) do { \
        const bf16* ks_ = kstg + (size_t)(kb_) * 64 * 64; \
        const bf16* vs_ = vstg + (size_t)(kb_) * 64; \
        gl_lds16(ks_,                   &Ks[cb_][r0][c0 * 8]); \
        gl_lds16(ks_ + 32 * 64,         &Ks[cb_][32 + r0][c0 * 8]); \
        gl_lds16(vs_,                   &Vs[cb_][r0][c0 * 8]); \
        gl_lds16(vs_ + (size_t)32 * T_, &Vs[cb_][32 + r0][c0 * 8]); \
    } while (0)

    const float NEGINF = -__builtin_inff();

    int qb = qt * 64 + wave * 16;
    int n  = qt + 1;
    int qrow = qb + lr;

    // read-side swizzled chunk offsets (loop-invariant per lane)
    int sw = lr & 7;
    int col0 = (lg ^ sw) * 8;           // chunk c2=0: (0*4+lg) ^ (row&7)
    int col1 = ((4 | lg) ^ sw) * 8;     // chunk c2=1: (1*4+lg) ^ (row&7)

    bf16x8 qf[2];
    #pragma unroll
    for (int c = 0; c < 2; ++c)
        qf[c] = *(const bf16x8*)(qp + (size_t)(qb + lr) * 64 + c * 32 + lg * 8);

    // all-ones A-frag for the l-sum MFMA (bf16 1.0 = 0x3F80)
    u32x4 onep;
    onep[0] = 0x3F803F80u; onep[1] = 0x3F803F80u; onep[2] = 0x3F803F80u; onep[3] = 0x3F803F80u;
    bf16x8 ones = __builtin_bit_cast(bf16x8, onep);

    f32x4 o[4] = {};
    f32x4 lacc = {};
    const f32x4 fz = {};           // loop-invariant zero C operand

    STAGE(0, 0);
    __syncthreads();               // drain DMA for tile 0
    int cur = 0;

    for (int kb = 0; kb < n; ++kb) {
        int kv = kb * 64;
        if (kb + 1 < n) STAGE(kb + 1, cur ^ 1);   // DMA overlaps compute below

        // S^T = K Q^T : rows = keys (A-frag from LDS), cols = q (lane lr)
        f32x4 s[4];
        __builtin_amdgcn_s_setprio(1);
        #pragma unroll
        for (int nt = 0; nt < 4; ++nt) {
            bf16x8 kf0 = *(const bf16x8*)(&Ks[cur][nt * 16 + lr][col0]);
            s[nt] = __builtin_amdgcn_mfma_f32_16x16x32_bf16(kf0, qf[0], fz, 0, 0, 0);
        }
        #pragma unroll
        for (int nt = 0; nt < 4; ++nt) {
            bf16x8 kf1 = *(const bf16x8*)(&Ks[cur][nt * 16 + lr][col1]);
            s[nt] = __builtin_amdgcn_mfma_f32_16x16x32_bf16(kf1, qf[1], s[nt], 0, 0, 0);
        }
        __builtin_amdgcn_s_setprio(0);
        // causal mask (diagonal tile only; Q pre-scaled by 0.125*log2e)
        if (kb == qt) {
            #pragma unroll
            for (int nt = 0; nt < 4; ++nt)
                #pragma unroll
                for (int r = 0; r < 4; ++r) {
                    int key = kv + nt * 16 + lg * 4 + r;
                    s[nt][r] = (key > qrow) ? NEGINF : s[nt][r];
                }
        }
        // fixed-max softmax: p = exp2(s); l accumulated on the MFMA pipe below
        #pragma unroll
        for (int nt = 0; nt < 4; ++nt)
            #pragma unroll
            for (int r = 0; r < 4; ++r)
                s[nt][r] = __builtin_amdgcn_exp2f(s[nt][r]);
        // P: S-frag -> PV B-frag entirely in registers (no LDS round-trip)
        unsigned int dpk[8];
        #pragma unroll
        for (int nt = 0; nt < 4; ++nt) {
            dpk[2*nt]   = cvtpk(s[nt][0], s[nt][1]);
            dpk[2*nt+1] = cvtpk(s[nt][2], s[nt][3]);
        }
        unsigned int pw[2][4];
        #pragma unroll
        for (int c2 = 0; c2 < 2; ++c2)
            #pragma unroll
            for (int pr = 0; pr < 2; ++pr) {
                unsigned int x = dpk[4*c2 + pr], y = dpk[4*c2 + 2 + pr];
                pswap32_16(x, y);
                pw[c2][pr] = x;      // word pr   (keys c2*32+lg*8 + {2pr,2pr+1})
                pw[c2][2+pr] = y;    // word pr+2 (keys c2*32+lg*8 + {4+2pr,5+2pr})
            }
        // O^T += V^T P^T ; l += 1^T P  (A=ones row-sums P on the MFMA pipe)
        __builtin_amdgcn_s_setprio(1);
        #pragma unroll
        for (int c2 = 0; c2 < 2; ++c2) {
            u32x4 pt;
            pt[0] = pw[c2][0]; pt[1] = pw[c2][1]; pt[2] = pw[c2][2]; pt[3] = pw[c2][3];
            bf16x8 pf = __builtin_bit_cast(bf16x8, pt);
            int vcol = c2 ? col1 : col0;
            #pragma unroll
            for (int dt = 0; dt < 4; ++dt) {
                bf16x8 vfr = *(const bf16x8*)(&Vs[cur][dt * 16 + lr][vcol]);
                o[dt] = __builtin_amdgcn_mfma_f32_16x16x32_bf16(vfr, pf, o[dt], 0, 0, 0);
            }
            lacc = __builtin_amdgcn_mfma_f32_16x16x32_bf16(ones, pf, lacc, 0, 0, 0);
        }
        __builtin_amdgcn_s_setprio(0);

        __syncthreads();           // drains next-tile DMA + all waves done with cur
        cur ^= 1;
    }
#undef STAGE

    // lacc[r] = full sum over ALL keys of P[.][lr] (identical across rows/lg)
    attn_store(o, lacc[0], ctx, b, qrow, h, lg);
}

// ---------------- launch ----------------
extern "C" void kernel_launch(void* const* d_in, const int* in_sizes, int n_in,
                              void* d_out, int out_size, void* d_ws, size_t ws_size,
                              hipStream_t stream) {
    const float* x  = (const float*)d_in[0];
    const float* wq = (const float*)d_in[1];
    const float* wk = (const float*)d_in[2];
    const float* wv = (const float*)d_in[3];
    const float* wo = (const float*)d_in[4];
    float* out = (float*)d_out;

    char* ws = (char*)d_ws;
    const size_t SZ_XB = (size_t)MTOT * C_ * sizeof(bf16);
    const size_t SZ_W  = (size_t)C_ * C_ * sizeof(bf16);
    bf16* xb  = (bf16*)(ws);
    bf16* wqb = (bf16*)(ws + SZ_XB);
    bf16* wkb = (bf16*)(ws + SZ_XB + SZ_W);
    bf16* wvb = (bf16*)(ws + SZ_XB + 2 * SZ_W);
    bf16* wob = (bf16*)(ws + SZ_XB + 3 * SZ_W);
    bf16* qb  = (bf16*)(ws + SZ_XB + 4 * SZ_W);
    bf16* kb  = (bf16*)(ws + 2 * SZ_XB + 4 * SZ_W);
    bf16* vtb = (bf16*)(ws + 3 * SZ_XB + 4 * SZ_W);
    bf16* ctb = (bf16*)(ws + 4 * SZ_XB + 4 * SZ_W);

    cvt_bf16<<<3072, 256, 0, stream>>>(x, xb, MTOT * C_ / 8);
    cvt_bf16_w4<<<dim3(288, 4), 256, 0, stream>>>(wq, wk, wv, wo, wqb, wkb, wvb, wob);

    gemm_qkv<<<dim3(MTOT / 256, C_ / 128, 3), 512, 0, stream>>>(xb, wqb, wkb, wvb, qb, kb, vtb);
    attn<<<1536, 256, 0, stream>>>(qb, kb, vtb, ctb);
    gemm_out<<<dim3(MTOT / 128, C_ / 128), 256, 0, stream>>>(ctb, wob, out);
}

// Round 14
// 219.353 us; speedup vs baseline: 1.0511x; 1.0511x over previous
//
#include <hip/hip_runtime.h>
#include <hip/hip_bf16.h>

#define B_  2
#define T_  4096
#define C_  768
#define H_  12
#define D_  64
#define MTOT (B_*T_)   // 8192

typedef __bf16 bf16;
typedef __bf16 bf16x8 __attribute__((ext_vector_type(8)));
typedef __bf16 bf16x4 __attribute__((ext_vector_type(4)));
typedef float  f32x4  __attribute__((ext_vector_type(4)));
typedef unsigned int u32x4 __attribute__((ext_vector_type(4)));

// async global->LDS, 16B per lane; LDS dest must be wave-uniform base + lane*16
__device__ __forceinline__ void gl_lds16(const bf16* g, bf16* l) {
    __builtin_amdgcn_global_load_lds(
        (const __attribute__((address_space(1))) void*)g,
        (__attribute__((address_space(3))) void*)l, 16, 0, 0);
}

// ---- P redistribution via permlane-swap BUILTINS ----
__device__ __forceinline__ void pswap32_16(unsigned int& x, unsigned int& y) {
    auto r1 = __builtin_amdgcn_permlane32_swap(x, y, false, false);
    auto r2 = __builtin_amdgcn_permlane16_swap(r1[0], r1[1], false, false);
    x = r2[0]; y = r2[1];
}
__device__ __forceinline__ unsigned int cvtpk(float lo, float hi) {
    unsigned int r;
    asm("v_cvt_pk_bf16_f32 %0, %1, %2" : "=v"(r) : "v"(lo), "v"(hi));
    return r;
}

// ---------------- fp32 -> bf16 convert ----------------
__global__ __launch_bounds__(256) void cvt_bf16(const float* __restrict__ src,
                                                bf16* __restrict__ dst, int n8) {
    int i = blockIdx.x * 256 + threadIdx.x;
    if (i >= n8) return;
    const float4* s4 = (const float4*)src;
    float4 a = s4[2*(size_t)i], b = s4[2*(size_t)i+1];
    bf16x8 o;
    o[0]=(bf16)a.x; o[1]=(bf16)a.y; o[2]=(bf16)a.z; o[3]=(bf16)a.w;
    o[4]=(bf16)b.x; o[5]=(bf16)b.y; o[6]=(bf16)b.z; o[7]=(bf16)b.w;
    *(bf16x8*)(dst + 8*(size_t)i) = o;
}

__global__ __launch_bounds__(256) void cvt_bf16_w4(const float* __restrict__ w0,
                                                   const float* __restrict__ w1,
                                                   const float* __restrict__ w2,
                                                   const float* __restrict__ w3,
                                                   bf16* __restrict__ d0,
                                                   bf16* __restrict__ d1,
                                                   bf16* __restrict__ d2,
                                                   bf16* __restrict__ d3) {
    int z = blockIdx.y;
    const float* src = (z==0)?w0:(z==1)?w1:(z==2)?w2:w3;
    bf16* dst = (z==0)?d0:(z==1)?d1:(z==2)?d2:d3;
    int i = blockIdx.x * 256 + threadIdx.x;
    const float4* s4 = (const float4*)src;
    float4 a = s4[2*(size_t)i], b = s4[2*(size_t)i+1];
    bf16x8 o;
    o[0]=(bf16)a.x; o[1]=(bf16)a.y; o[2]=(bf16)a.z; o[3]=(bf16)a.w;
    o[4]=(bf16)b.x; o[5]=(bf16)b.y; o[6]=(bf16)b.z; o[7]=(bf16)b.w;
    *(bf16x8*)(dst + 8*(size_t)i) = o;
}

// ---------------- QKV projection GEMM (round-8/11 proven structure) ---------
// GEMM levers exhausted (r8 dbuf neutral, r9 depth -23µs, r12 swizzle
// neutral, r13 -26% traffic +4µs) — pinned at the round-8 form.
// z=0 -> Q (pre-scaled by 0.125*log2e) in (B,H,T,D); z=1 -> K; z=2 -> V^T.
__global__ __launch_bounds__(256) void gemm_qkv(const bf16* __restrict__ xb,
                                                const bf16* __restrict__ wqb,
                                                const bf16* __restrict__ wkb,
                                                const bf16* __restrict__ wvb,
                                                bf16* __restrict__ qo,
                                                bf16* __restrict__ ko,
                                                bf16* __restrict__ vto) {
    int z = blockIdx.z;
    const bf16* w = (z == 0) ? wqb : (z == 1) ? wkb : wvb;
    bf16* dst = (z == 0) ? qo : (z == 1) ? ko : vto;
    int mbase = blockIdx.x * 128;
    int nbase = blockIdx.y * 128;
    __shared__ bf16 As[2][128][32];   // UNPADDED: global_load_lds lane-contiguous
    __shared__ bf16 Bs[2][128][32];
    int tid  = threadIdx.x;
    int wave = tid >> 6, lane = tid & 63;
    int wm = (wave >> 1) * 64, wn = (wave & 1) * 64;
    int lr = lane & 15, lg = lane >> 4;
    int srow0 = tid >> 2, scol0 = tid & 3;
    int srow1 = (tid + 256) >> 2, scol1 = (tid + 256) & 3;
    const bf16* xa0 = xb + (size_t)(mbase + srow0) * C_ + scol0 * 8;
    const bf16* xa1 = xb + (size_t)(mbase + srow1) * C_ + scol1 * 8;
    const bf16* wa0 = w  + (size_t)(nbase + srow0) * C_ + scol0 * 8;
    const bf16* wa1 = w  + (size_t)(nbase + srow1) * C_ + scol1 * 8;
#define GSTAGE(kb_, cb_) do { \
        gl_lds16(xa0 + (kb_), &As[cb_][srow0][scol0 * 8]); \
        gl_lds16(xa1 + (kb_), &As[cb_][srow1][scol1 * 8]); \
        gl_lds16(wa0 + (kb_), &Bs[cb_][srow0][scol0 * 8]); \
        gl_lds16(wa1 + (kb_), &Bs[cb_][srow1][scol1 * 8]); \
    } while (0)
    f32x4 acc[4][4] = {};
    GSTAGE(0, 0);
    __syncthreads();               // drain DMA for tile 0
    int cur = 0;
    for (int kb = 0; kb < C_; kb += 32) {
        if (kb + 32 < C_) GSTAGE(kb + 32, cur ^ 1);   // DMA overlaps compute
        bf16x8 af[4], bfr[4];
        #pragma unroll
        for (int mt = 0; mt < 4; ++mt) af[mt]  = *(const bf16x8*)(&As[cur][wm + mt*16 + lr][lg*8]);
        #pragma unroll
        for (int nt = 0; nt < 4; ++nt) bfr[nt] = *(const bf16x8*)(&Bs[cur][wn + nt*16 + lr][lg*8]);
        #pragma unroll
        for (int mt = 0; mt < 4; ++mt)
            #pragma unroll
            for (int nt = 0; nt < 4; ++nt)
                acc[mt][nt] = __builtin_amdgcn_mfma_f32_16x16x32_bf16(af[mt], bfr[nt], acc[mt][nt], 0, 0, 0);
        __syncthreads();           // next-tile DMA landed + all reads of cur done
        cur ^= 1;
    }
#undef GSTAGE
    float sc = (z == 0) ? 0.18033688011112042f : 1.0f;  // 0.125*log2(e) folded into Q
    int m0 = mbase + wm + (lg << 2);
    int n0 = nbase + wn + lr;
    if (z < 2) {
        #pragma unroll
        for (int mt = 0; mt < 4; ++mt) {
            #pragma unroll
            for (int nt = 0; nt < 4; ++nt) {
                int n = n0 + nt * 16;
                int h = n >> 6, d = n & 63;
                #pragma unroll
                for (int r = 0; r < 4; ++r) {
                    int m = m0 + mt * 16 + r;
                    int b = m >> 12, t = m & 4095;
                    dst[(((size_t)b * H_ + h) * T_ + t) * 64 + d] = (bf16)(acc[mt][nt][r] * sc);
                }
            }
        }
    } else {
        #pragma unroll
        for (int mt = 0; mt < 4; ++mt) {
            int m = m0 + mt * 16;
            int b = m >> 12, t = m & 4095;
            #pragma unroll
            for (int nt = 0; nt < 4; ++nt) {
                int n = n0 + nt * 16;
                int h = n >> 6, d = n & 63;
                bf16x4 pk;
                #pragma unroll
                for (int r = 0; r < 4; ++r) pk[r] = (bf16)acc[mt][nt][r];
                *(bf16x4*)(dst + (((size_t)b * H_ + h) * 64 + d) * T_ + t) = pk;
            }
        }
    }
}

// ---------------- output projection GEMM (round-8 structure) ----------------
__global__ __launch_bounds__(256) void gemm_out(const bf16* __restrict__ ctx,
                                                const bf16* __restrict__ wob,
                                                float* __restrict__ out) {
    int mbase = blockIdx.x * 128;
    int nbase = blockIdx.y * 128;
    __shared__ bf16 As[2][128][32];
    __shared__ bf16 Bs[2][128][32];
    int tid  = threadIdx.x;
    int wave = tid >> 6, lane = tid & 63;
    int wm = (wave >> 1) * 64, wn = (wave & 1) * 64;
    int lr = lane & 15, lg = lane >> 4;
    int srow0 = tid >> 2, scol0 = tid & 3;
    int srow1 = (tid + 256) >> 2, scol1 = (tid + 256) & 3;
    const bf16* xa0 = ctx + (size_t)(mbase + srow0) * C_ + scol0 * 8;
    const bf16* xa1 = ctx + (size_t)(mbase + srow1) * C_ + scol1 * 8;
    const bf16* wa0 = wob + (size_t)(nbase + srow0) * C_ + scol0 * 8;
    const bf16* wa1 = wob + (size_t)(nbase + srow1) * C_ + scol1 * 8;
#define GSTAGE(kb_, cb_) do { \
        gl_lds16(xa0 + (kb_), &As[cb_][srow0][scol0 * 8]); \
        gl_lds16(xa1 + (kb_), &As[cb_][srow1][scol1 * 8]); \
        gl_lds16(wa0 + (kb_), &Bs[cb_][srow0][scol0 * 8]); \
        gl_lds16(wa1 + (kb_), &Bs[cb_][srow1][scol1 * 8]); \
    } while (0)
    f32x4 acc[4][4] = {};
    GSTAGE(0, 0);
    __syncthreads();
    int cur = 0;
    for (int kb = 0; kb < C_; kb += 32) {
        if (kb + 32 < C_) GSTAGE(kb + 32, cur ^ 1);
        bf16x8 af[4], bfr[4];
        #pragma unroll
        for (int mt = 0; mt < 4; ++mt) af[mt]  = *(const bf16x8*)(&As[cur][wm + mt*16 + lr][lg*8]);
        #pragma unroll
        for (int nt = 0; nt < 4; ++nt) bfr[nt] = *(const bf16x8*)(&Bs[cur][wn + nt*16 + lr][lg*8]);
        #pragma unroll
        for (int mt = 0; mt < 4; ++mt)
            #pragma unroll
            for (int nt = 0; nt < 4; ++nt)
                acc[mt][nt] = __builtin_amdgcn_mfma_f32_16x16x32_bf16(af[mt], bfr[nt], acc[mt][nt], 0, 0, 0);
        __syncthreads();
        cur ^= 1;
    }
#undef GSTAGE
    int m0 = mbase + wm + (lg << 2);
    int n0 = nbase + wn + lr;
    #pragma unroll
    for (int mt = 0; mt < 4; ++mt)
        #pragma unroll
        for (int nt = 0; nt < 4; ++nt)
            #pragma unroll
            for (int r = 0; r < 4; ++r)
                out[(size_t)(m0 + mt * 16 + r) * C_ + n0 + nt * 16] = acc[mt][nt][r];
}

// ---------------- causal flash attention (round-14: paired q-tiles, lean) ---
// attn is latency-quantized: per block-iter wall ~1070 cyc vs ~400 cyc pipe
// demand — the residue is barrier+DMA-drain paid per iteration. Pairing
// amortizes exactly that: block owns qlo=idx/24 AND qhi=63-qlo (weight 65
// for EVERY block -> grid 768 fully co-resident, zero drain tail). During
// the paired phase (kb<=qlo, 51% of all tile-work) one barrier+stage serves
// TWO q-tiles and every K/V-frag LDS read feeds 2 MFMAs. Round-1's pairing
// was neutral because the then-dominant serial softmax isn't amortized by
// pairing — that cost was removed in rounds 6/10. Two separate loops (no
// per-iter branch — round-10 bloat lesson); no launch_bounds cap (round-4
// spill lesson; WRITE_SIZE is the spill falsifier).
__device__ __forceinline__ void attn_store(const f32x4 (&o)[4], float l, bf16* __restrict__ ctx,
                                           int b, int qrow, int h, int lg) {
    float inv = 1.0f / l;
    #pragma unroll
    for (int dt = 0; dt < 4; ++dt) {
        bf16x4 pk;
        #pragma unroll
        for (int r = 0; r < 4; ++r) pk[r] = (bf16)(o[dt][r] * inv);
        *(bf16x4*)(ctx + ((size_t)b * T_ + qrow) * C_ + h * 64 + dt * 16 + lg * 4) = pk;
    }
}

__global__ __launch_bounds__(256) void attn(const bf16* __restrict__ q,
                                            const bf16* __restrict__ k,
                                            const bf16* __restrict__ vt,
                                            bf16* __restrict__ ctx) {
    int idx = blockIdx.x;          // 0..767
    int qlo = idx / 24;            // 0..31
    int qhi = 63 - qlo;            // 63..32 (always > qlo)
    int bh  = idx % 24;
    int b = bh / H_, h = bh % H_;
    int tid = threadIdx.x;
    int wave = tid >> 6, lane = tid & 63;
    int lr = lane & 15, lg = lane >> 4;

    __shared__ bf16 Ks[2][64][64]; // double-buffered K tile (keys x d), swizzled
    __shared__ bf16 Vs[2][64][64]; // double-buffered V^T tile (d x keys), swizzled

    const bf16* qp = q  + (size_t)bh * T_ * 64;
    const bf16* kp = k  + (size_t)bh * T_ * 64;
    const bf16* vp = vt + (size_t)bh * 64 * (size_t)T_;

    // staging: thread tid owns LDS 16B chunk (row r0, chunk c0) = linear tid*16;
    // source column pre-swizzled so LDS[row][j] = G[row][j ^ (row&7)]
    int r0 = tid >> 3, c0 = tid & 7;
    int cs = (c0 ^ (r0 & 7)) * 8;                    // swizzled source col (elems)
    const bf16* kstg = kp + (size_t)r0 * 64 + cs;
    const bf16* vstg = vp + (size_t)r0 * T_ + cs;

#define STAGE(kb_, cb_) do { \
        const bf16* ks_ = kstg + (size_t)(kb_) * 64 * 64; \
        const bf16* vs_ = vstg + (size_t)(kb_) * 64; \
        gl_lds16(ks_,                   &Ks[cb_][r0][c0 * 8]); \
        gl_lds16(ks_ + 32 * 64,         &Ks[cb_][32 + r0][c0 * 8]); \
        gl_lds16(vs_,                   &Vs[cb_][r0][c0 * 8]); \
        gl_lds16(vs_ + (size_t)32 * T_, &Vs[cb_][32 + r0][c0 * 8]); \
    } while (0)

    const float NEGINF = -__builtin_inff();

    int qbA = qlo * 64 + wave * 16;
    int qbB = qhi * 64 + wave * 16;
    int qrowA = qbA + lr, qrowB = qbB + lr;
    int n = qhi + 1;

    // read-side swizzled chunk offsets (loop-invariant per lane)
    int sw = lr & 7;
    int col0 = (lg ^ sw) * 8;           // chunk c2=0: (0*4+lg) ^ (row&7)
    int col1 = ((4 | lg) ^ sw) * 8;     // chunk c2=1: (1*4+lg) ^ (row&7)

    bf16x8 qfA[2], qfB[2];
    #pragma unroll
    for (int c = 0; c < 2; ++c) {
        qfA[c] = *(const bf16x8*)(qp + (size_t)(qbA + lr) * 64 + c * 32 + lg * 8);
        qfB[c] = *(const bf16x8*)(qp + (size_t)(qbB + lr) * 64 + c * 32 + lg * 8);
    }

    // all-ones A-frag for the l-sum MFMA (bf16 1.0 = 0x3F80)
    u32x4 onep;
    onep[0] = 0x3F803F80u; onep[1] = 0x3F803F80u; onep[2] = 0x3F803F80u; onep[3] = 0x3F803F80u;
    bf16x8 ones = __builtin_bit_cast(bf16x8, onep);

    f32x4 oA[4] = {}, oB[4] = {};
    f32x4 laccA = {}, laccB = {};
    const f32x4 fz = {};           // loop-invariant zero C operand

    STAGE(0, 0);
    __syncthreads();               // drain DMA for tile 0
    int cur = 0;

    // ---- paired phase: kb = 0..qlo (both tiles active) ----
    for (int kb = 0; kb <= qlo; ++kb) {
        if (kb + 1 < n) STAGE(kb + 1, cur ^ 1);   // DMA overlaps compute below

        f32x4 sA[4], sB[4];
        __builtin_amdgcn_s_setprio(1);
        #pragma unroll
        for (int nt = 0; nt < 4; ++nt) {
            bf16x8 kf0 = *(const bf16x8*)(&Ks[cur][nt * 16 + lr][col0]);
            sB[nt] = __builtin_amdgcn_mfma_f32_16x16x32_bf16(kf0, qfB[0], fz, 0, 0, 0);
            sA[nt] = __builtin_amdgcn_mfma_f32_16x16x32_bf16(kf0, qfA[0], fz, 0, 0, 0);
        }
        #pragma unroll
        for (int nt = 0; nt < 4; ++nt) {
            bf16x8 kf1 = *(const bf16x8*)(&Ks[cur][nt * 16 + lr][col1]);
            sB[nt] = __builtin_amdgcn_mfma_f32_16x16x32_bf16(kf1, qfB[1], sB[nt], 0, 0, 0);
            sA[nt] = __builtin_amdgcn_mfma_f32_16x16x32_bf16(kf1, qfA[1], sA[nt], 0, 0, 0);
        }
        __builtin_amdgcn_s_setprio(0);
        // tile-A diagonal mask (kb==qlo is the last paired iter)
        if (kb == qlo) {
            int kv = kb * 64;
            #pragma unroll
            for (int nt = 0; nt < 4; ++nt)
                #pragma unroll
                for (int r = 0; r < 4; ++r) {
                    int key = kv + nt * 16 + lg * 4 + r;
                    sA[nt][r] = (key > qrowA) ? NEGINF : sA[nt][r];
                }
        }
        // fixed-max softmax both tiles
        #pragma unroll
        for (int nt = 0; nt < 4; ++nt)
            #pragma unroll
            for (int r = 0; r < 4; ++r) {
                sB[nt][r] = __builtin_amdgcn_exp2f(sB[nt][r]);
                sA[nt][r] = __builtin_amdgcn_exp2f(sA[nt][r]);
            }
        // pack both tiles: S-frag -> PV B-frag in registers
        unsigned int pwA[2][4], pwB[2][4];
        {
            unsigned int dpk[8];
            #pragma unroll
            for (int nt = 0; nt < 4; ++nt) {
                dpk[2*nt]   = cvtpk(sB[nt][0], sB[nt][1]);
                dpk[2*nt+1] = cvtpk(sB[nt][2], sB[nt][3]);
            }
            #pragma unroll
            for (int c2 = 0; c2 < 2; ++c2)
                #pragma unroll
                for (int pr = 0; pr < 2; ++pr) {
                    unsigned int x = dpk[4*c2 + pr], y = dpk[4*c2 + 2 + pr];
                    pswap32_16(x, y);
                    pwB[c2][pr] = x; pwB[c2][2+pr] = y;
                }
            #pragma unroll
            for (int nt = 0; nt < 4; ++nt) {
                dpk[2*nt]   = cvtpk(sA[nt][0], sA[nt][1]);
                dpk[2*nt+1] = cvtpk(sA[nt][2], sA[nt][3]);
            }
            #pragma unroll
            for (int c2 = 0; c2 < 2; ++c2)
                #pragma unroll
                for (int pr = 0; pr < 2; ++pr) {
                    unsigned int x = dpk[4*c2 + pr], y = dpk[4*c2 + 2 + pr];
                    pswap32_16(x, y);
                    pwA[c2][pr] = x; pwA[c2][2+pr] = y;
                }
        }
        // fused PV: each V-frag read feeds both tiles; l-sums on MFMA pipe
        __builtin_amdgcn_s_setprio(1);
        #pragma unroll
        for (int c2 = 0; c2 < 2; ++c2) {
            u32x4 ptB, ptA;
            ptB[0]=pwB[c2][0]; ptB[1]=pwB[c2][1]; ptB[2]=pwB[c2][2]; ptB[3]=pwB[c2][3];
            ptA[0]=pwA[c2][0]; ptA[1]=pwA[c2][1]; ptA[2]=pwA[c2][2]; ptA[3]=pwA[c2][3];
            bf16x8 pfB = __builtin_bit_cast(bf16x8, ptB);
            bf16x8 pfA = __builtin_bit_cast(bf16x8, ptA);
            int vcol = c2 ? col1 : col0;
            #pragma unroll
            for (int dt = 0; dt < 4; ++dt) {
                bf16x8 vfr = *(const bf16x8*)(&Vs[cur][dt * 16 + lr][vcol]);
                oB[dt] = __builtin_amdgcn_mfma_f32_16x16x32_bf16(vfr, pfB, oB[dt], 0, 0, 0);
                oA[dt] = __builtin_amdgcn_mfma_f32_16x16x32_bf16(vfr, pfA, oA[dt], 0, 0, 0);
            }
            laccB = __builtin_amdgcn_mfma_f32_16x16x32_bf16(ones, pfB, laccB, 0, 0, 0);
            laccA = __builtin_amdgcn_mfma_f32_16x16x32_bf16(ones, pfA, laccA, 0, 0, 0);
        }
        __builtin_amdgcn_s_setprio(0);

        __syncthreads();           // drains next-tile DMA + all waves done with cur
        cur ^= 1;
    }

    // ---- single phase: kb = qlo+1..qhi (only tile B active) ----
    for (int kb = qlo + 1; kb < n; ++kb) {
        if (kb + 1 < n) STAGE(kb + 1, cur ^ 1);

        f32x4 s[4];
        __builtin_amdgcn_s_setprio(1);
        #pragma unroll
        for (int nt = 0; nt < 4; ++nt) {
            bf16x8 kf0 = *(const bf16x8*)(&Ks[cur][nt * 16 + lr][col0]);
            s[nt] = __builtin_amdgcn_mfma_f32_16x16x32_bf16(kf0, qfB[0], fz, 0, 0, 0);
        }
        #pragma unroll
        for (int nt = 0; nt < 4; ++nt) {
            bf16x8 kf1 = *(const bf16x8*)(&Ks[cur][nt * 16 + lr][col1]);
            s[nt] = __builtin_amdgcn_mfma_f32_16x16x32_bf16(kf1, qfB[1], s[nt], 0, 0, 0);
        }
        __builtin_amdgcn_s_setprio(0);
        // tile-B diagonal mask (kb==qhi is the last iter)
        if (kb == qhi) {
            int kv = kb * 64;
            #pragma unroll
            for (int nt = 0; nt < 4; ++nt)
                #pragma unroll
                for (int r = 0; r < 4; ++r) {
                    int key = kv + nt * 16 + lg * 4 + r;
                    s[nt][r] = (key > qrowB) ? NEGINF : s[nt][r];
                }
        }
        #pragma unroll
        for (int nt = 0; nt < 4; ++nt)
            #pragma unroll
            for (int r = 0; r < 4; ++r)
                s[nt][r] = __builtin_amdgcn_exp2f(s[nt][r]);
        unsigned int dpk[8];
        #pragma unroll
        for (int nt = 0; nt < 4; ++nt) {
            dpk[2*nt]   = cvtpk(s[nt][0], s[nt][1]);
            dpk[2*nt+1] = cvtpk(s[nt][2], s[nt][3]);
        }
        unsigned int pw[2][4];
        #pragma unroll
        for (int c2 = 0; c2 < 2; ++c2)
            #pragma unroll
            for (int pr = 0; pr < 2; ++pr) {
                unsigned int x = dpk[4*c2 + pr], y = dpk[4*c2 + 2 + pr];
                pswap32_16(x, y);
                pw[c2][pr] = x; pw[c2][2+pr] = y;
            }
        __builtin_amdgcn_s_setprio(1);
        #pragma unroll
        for (int c2 = 0; c2 < 2; ++c2) {
            u32x4 pt;
            pt[0] = pw[c2][0]; pt[1] = pw[c2][1]; pt[2] = pw[c2][2]; pt[3] = pw[c2][3];
            bf16x8 pf = __builtin_bit_cast(bf16x8, pt);
            int vcol = c2 ? col1 : col0;
            #pragma unroll
            for (int dt = 0; dt < 4; ++dt) {
                bf16x8 vfr = *(const bf16x8*)(&Vs[cur][dt * 16 + lr][vcol]);
                oB[dt] = __builtin_amdgcn_mfma_f32_16x16x32_bf16(vfr, pf, oB[dt], 0, 0, 0);
            }
            laccB = __builtin_amdgcn_mfma_f32_16x16x32_bf16(ones, pf, laccB, 0, 0, 0);
        }
        __builtin_amdgcn_s_setprio(0);

        __syncthreads();
        cur ^= 1;
    }
#undef STAGE

    attn_store(oA, laccA[0], ctx, b, qrowA, h, lg);
    attn_store(oB, laccB[0], ctx, b, qrowB, h, lg);
}

// ---------------- launch ----------------
extern "C" void kernel_launch(void* const* d_in, const int* in_sizes, int n_in,
                              void* d_out, int out_size, void* d_ws, size_t ws_size,
                              hipStream_t stream) {
    const float* x  = (const float*)d_in[0];
    const float* wq = (const float*)d_in[1];
    const float* wk = (const float*)d_in[2];
    const float* wv = (const float*)d_in[3];
    const float* wo = (const float*)d_in[4];
    float* out = (float*)d_out;

    char* ws = (char*)d_ws;
    const size_t SZ_XB = (size_t)MTOT * C_ * sizeof(bf16);
    const size_t SZ_W  = (size_t)C_ * C_ * sizeof(bf16);
    bf16* xb  = (bf16*)(ws);
    bf16* wqb = (bf16*)(ws + SZ_XB);
    bf16* wkb = (bf16*)(ws + SZ_XB + SZ_W);
    bf16* wvb = (bf16*)(ws + SZ_XB + 2 * SZ_W);
    bf16* wob = (bf16*)(ws + SZ_XB + 3 * SZ_W);
    bf16* qb  = (bf16*)(ws + SZ_XB + 4 * SZ_W);
    bf16* kb  = (bf16*)(ws + 2 * SZ_XB + 4 * SZ_W);
    bf16* vtb = (bf16*)(ws + 3 * SZ_XB + 4 * SZ_W);
    bf16* ctb = (bf16*)(ws + 4 * SZ_XB + 4 * SZ_W);

    cvt_bf16<<<3072, 256, 0, stream>>>(x, xb, MTOT * C_ / 8);
    cvt_bf16_w4<<<dim3(288, 4), 256, 0, stream>>>(wq, wk, wv, wo, wqb, wkb, wvb, wob);

    gemm_qkv<<<dim3(MTOT / 128, C_ / 128, 3), 256, 0, stream>>>(xb, wqb, wkb, wvb, qb, kb, vtb);
    attn<<<768, 256, 0, stream>>>(qb, kb, vtb, ctb);
    gemm_out<<<dim3(MTOT / 128, C_ / 128), 256, 0, stream>>>(ctb, wob, out);
}